// Round 12
// baseline (108.573 us; speedup 1.0000x reference)
//
#include <hip/hip_runtime.h>
#include <hip/hip_bf16.h>
#include <math.h>

#define NN 1024   // nodes
#define FD 64     // features
#define EE 65536  // edges
#define HD 32     // hidden
#define WSTRIDE 136  // LDS row stride in shorts (128 + 8 pad: 2-way banks, 16B-aligned)

typedef __attribute__((ext_vector_type(8))) short short8;
typedef __attribute__((ext_vector_type(4))) float floatx4;

__device__ __forceinline__ float sigmoid_f(float z) {
  return 1.0f / (1.0f + expf(-z));
}
__device__ __forceinline__ float sigmoid_fast(float z) {
  return 1.0f / (1.0f + __expf(-z));
}

__device__ __forceinline__ unsigned pack_bf16_trunc(float hi, float lo) {
  unsigned a = __builtin_bit_cast(unsigned, hi);
  unsigned b = __builtin_bit_cast(unsigned, lo);
  return __builtin_amdgcn_perm(a, b, 0x07060302u);
}

__device__ __forceinline__ short8 pack8(const float* v) {
  union { unsigned u[4]; short8 s; } p;
#pragma unroll
  for (int t = 0; t < 4; ++t) p.u[t] = pack_bf16_trunc(v[2 * t + 1], v[2 * t]);
  return p.s;
}

struct Frag3 { short8 a0, a1, a2; };

// 3-way bf16 split (exact: 8+8+8 mantissa bits) of 8 fp32 values.
__device__ __forceinline__ Frag3 split_pack(const float* v) {
  float r[8], r2[8];
#pragma unroll
  for (int t = 0; t < 8; ++t) {
    const unsigned uv = __builtin_bit_cast(unsigned, v[t]);
    const float f0 = __builtin_bit_cast(float, uv & 0xFFFF0000u);
    const float rr = v[t] - f0;
    const unsigned ur = __builtin_bit_cast(unsigned, rr);
    const float f1 = __builtin_bit_cast(float, ur & 0xFFFF0000u);
    r[t] = rr;
    r2[t] = rr - f1;
  }
  Frag3 f;
  f.a0 = pack8(v);
  f.a1 = pack8(r);
  f.a2 = pack8(r2);
  return f;
}

// ---------------------------------------------------------------------------
// Pre-pass: pre[which][node][h]; block 256 builds Wt0/1/2 splits.
// ---------------------------------------------------------------------------
__global__ __launch_bounds__(256) void pre_kernel3(
    const float* __restrict__ x, const float* __restrict__ W1,
    const float* __restrict__ b1, float* __restrict__ pre,
    short* __restrict__ Wt0, short* __restrict__ Wt1, short* __restrict__ Wt2) {
  const int blk = blockIdx.x;
  const int t = threadIdx.x;
  if (blk < 256) {
    const int node = blk * 4 + (t >> 6);
    const int which = (t >> 5) & 1;
    const int h = t & 31;
    const float* xr = x + node * FD;
    const float* wp = W1 + which * FD * HD + h;
    float a0 = which ? 0.0f : b1[h], a1 = 0.0f, a2 = 0.0f, a3 = 0.0f;
#pragma unroll
    for (int f = 0; f < FD; f += 4) {
      a0 = fmaf(xr[f + 0], wp[(f + 0) * HD], a0);
      a1 = fmaf(xr[f + 1], wp[(f + 1) * HD], a1);
      a2 = fmaf(xr[f + 2], wp[(f + 2) * HD], a2);
      a3 = fmaf(xr[f + 3], wp[(f + 3) * HD], a3);
    }
    pre[which * (NN * HD) + node * HD + h] = (a0 + a1) + (a2 + a3);
  } else {
    for (int idx = t; idx < 32 * 128; idx += 256) {
      const int h = idx >> 7;
      const int k = idx & 127;
      const int f = k & 63;
      const int b = 2 + (k >> 6);
      const float v = W1[(b * FD + f) * HD + h];
      const unsigned uv = __builtin_bit_cast(unsigned, v);
      const unsigned u0 = uv & 0xFFFF0000u;
      const float f0 = __builtin_bit_cast(float, u0);
      const float r = v - f0;
      const unsigned u1 = __builtin_bit_cast(unsigned, r) & 0xFFFF0000u;
      const float f1 = __builtin_bit_cast(float, u1);
      const float r2 = r - f1;
      const unsigned u2 = __builtin_bit_cast(unsigned, r2) & 0xFFFF0000u;
      Wt0[idx] = (short)(u0 >> 16);
      Wt1[idx] = (short)(u1 >> 16);
      Wt2[idx] = (short)(u2 >> 16);
    }
  }
}

// ---------------------------------------------------------------------------
// Edge helper: 12 split-MFMAs for one 8-feature chunk. A-frags from LDS.
// ---------------------------------------------------------------------------
__device__ __forceinline__ void edge_chunk(
    const float* feat, const short* sWt0, const short* sWt1, const short* sWt2,
    int c, int q, int kc, floatx4& acc0, floatx4& acc1) {
  const Frag3 B = split_pack(feat);
  const int off0 = c * WSTRIDE + kc * 32 + q * 8;
  const int off1 = (16 + c) * WSTRIDE + kc * 32 + q * 8;
  const short8 A00 = *(const short8*)(sWt0 + off0);
  const short8 A01 = *(const short8*)(sWt1 + off0);
  const short8 A02 = *(const short8*)(sWt2 + off0);
  const short8 A10 = *(const short8*)(sWt0 + off1);
  const short8 A11 = *(const short8*)(sWt1 + off1);
  const short8 A12 = *(const short8*)(sWt2 + off1);
  acc0 = __builtin_amdgcn_mfma_f32_16x16x32_bf16(A00, B.a0, acc0, 0, 0, 0);
  acc0 = __builtin_amdgcn_mfma_f32_16x16x32_bf16(A01, B.a0, acc0, 0, 0, 0);
  acc0 = __builtin_amdgcn_mfma_f32_16x16x32_bf16(A02, B.a0, acc0, 0, 0, 0);
  acc0 = __builtin_amdgcn_mfma_f32_16x16x32_bf16(A00, B.a1, acc0, 0, 0, 0);
  acc0 = __builtin_amdgcn_mfma_f32_16x16x32_bf16(A01, B.a1, acc0, 0, 0, 0);
  acc0 = __builtin_amdgcn_mfma_f32_16x16x32_bf16(A00, B.a2, acc0, 0, 0, 0);
  acc1 = __builtin_amdgcn_mfma_f32_16x16x32_bf16(A10, B.a0, acc1, 0, 0, 0);
  acc1 = __builtin_amdgcn_mfma_f32_16x16x32_bf16(A11, B.a0, acc1, 0, 0, 0);
  acc1 = __builtin_amdgcn_mfma_f32_16x16x32_bf16(A12, B.a0, acc1, 0, 0, 0);
  acc1 = __builtin_amdgcn_mfma_f32_16x16x32_bf16(A10, B.a1, acc1, 0, 0, 0);
  acc1 = __builtin_amdgcn_mfma_f32_16x16x32_bf16(A11, B.a1, acc1, 0, 0, 0);
  acc1 = __builtin_amdgcn_mfma_f32_16x16x32_bf16(A10, B.a2, acc1, 0, 0, 0);
}

// ---------------------------------------------------------------------------
// Fused edge+dense kernel. Wt in LDS (R11) + amdgpu_waves_per_eu(2,2):
// pins the allocator's occupancy target at 2 waves/EU (~ the measured
// residency anyway) so hoisted per-wave state stays in VGPRs instead of
// being rematerialized/spilled per iteration (R10: VGPR=84 pathology).
// ---------------------------------------------------------------------------
#define DENSE_BLOCKS 520

__global__ __launch_bounds__(256)
__attribute__((amdgpu_waves_per_eu(2, 2)))
void fused_mfma_kernel(
    const float* __restrict__ x, const int* __restrict__ eidx,
    const float* __restrict__ pre, const short* __restrict__ Wt0,
    const short* __restrict__ Wt1, const short* __restrict__ Wt2,
    const float* __restrict__ W2, const float* __restrict__ b2,
    float* __restrict__ out, float* __restrict__ outP) {
  __shared__ short sWt0[32 * WSTRIDE];
  __shared__ short sWt1[32 * WSTRIDE];
  __shared__ short sWt2[32 * WSTRIDE];
  __shared__ float mir[4][256];

  // ---- stage Wt into LDS (vectorized, one-time) ----
  for (int idx = threadIdx.x; idx < 512; idx += 256) {
    const int h = idx >> 4;
    const int kk = (idx & 15) * 8;
    *(short8*)(sWt0 + h * WSTRIDE + kk) = *(const short8*)(Wt0 + h * 128 + kk);
    *(short8*)(sWt1 + h * WSTRIDE + kk) = *(const short8*)(Wt1 + h * 128 + kk);
    *(short8*)(sWt2 + h * WSTRIDE + kk) = *(const short8*)(Wt2 + h * 128 + kk);
  }
  __syncthreads();

  const int lane = threadIdx.x & 63;
  const int w = threadIdx.x >> 6;
  const int q = lane >> 4;
  const int c = lane & 15;

  if (blockIdx.x < DENSE_BLOCKS) {
    // ---------------- dense path: symmetric bilinear, triangular tiling ----
    const int T = blockIdx.x * 4 + w;
    int a = (int)((sqrtf(8.0f * (float)T + 1.0f) - 1.0f) * 0.5f);
    while ((a + 1) * (a + 2) / 2 <= T) ++a;
    while (a * (a + 1) / 2 > T) --a;
    const int b = T - a * (a + 1) / 2;
    const int j0 = a * 16;
    const int i0 = b * 16;
    const bool offdiag = (a != b);

    const float* xj = x + (size_t)(j0 + c) * FD;
    float jA[8], jB[8];
#pragma unroll
    for (int t = 0; t < 4; ++t) {
      jA[t] = xj[q * 8 + t];      jA[4 + t] = xj[q * 8 + 4 + t];
      jB[t] = xj[32 + q * 8 + t]; jB[4 + t] = xj[32 + q * 8 + 4 + t];
    }

    const floatx4 psA_j = *(const floatx4*)(pre + (j0 + c) * HD + q * 4);
    const floatx4 psB_j = *(const floatx4*)(pre + (j0 + c) * HD + 16 + q * 4);
    const floatx4 pdA_j = *(const floatx4*)(pre + NN * HD + (j0 + c) * HD + q * 4);
    const floatx4 pdB_j = *(const floatx4*)(pre + NN * HD + (j0 + c) * HD + 16 + q * 4);
    const floatx4 w2A = *(const floatx4*)(W2 + q * 4);
    const floatx4 w2B = *(const floatx4*)(W2 + 16 + q * 4);
    const float b2v = b2[0];

    for (int ii = 0; ii < 16; ++ii) {
      const int i = i0 + ii;
      const float* xi = x + (size_t)i * FD;
      const floatx4 psA_i = *(const floatx4*)(pre + i * HD + q * 4);
      const floatx4 psB_i = *(const floatx4*)(pre + i * HD + 16 + q * 4);
      floatx4 acc0 = {0.0f, 0.0f, 0.0f, 0.0f};
      floatx4 acc1 = {0.0f, 0.0f, 0.0f, 0.0f};

      {
        const floatx4 i0v = *(const floatx4*)(xi + q * 8);
        const floatx4 i1v = *(const floatx4*)(xi + q * 8 + 4);
        float ad[8], pr[8];
#pragma unroll
        for (int t = 0; t < 4; ++t) {
          ad[t] = fabsf(i0v[t] - jA[t]);         pr[t] = i0v[t] * jA[t];
          ad[4 + t] = fabsf(i1v[t] - jA[4 + t]); pr[4 + t] = i1v[t] * jA[4 + t];
        }
        const short8 fad = pack8(ad);
        const short8 fpr = pack8(pr);
        const short8 A00 = *(const short8*)(sWt0 + c * WSTRIDE + q * 8);
        const short8 A10 = *(const short8*)(sWt0 + (16 + c) * WSTRIDE + q * 8);
        const short8 A02 = *(const short8*)(sWt0 + c * WSTRIDE + 64 + q * 8);
        const short8 A12 = *(const short8*)(sWt0 + (16 + c) * WSTRIDE + 64 + q * 8);
        acc0 = __builtin_amdgcn_mfma_f32_16x16x32_bf16(A00, fad, acc0, 0, 0, 0);
        acc1 = __builtin_amdgcn_mfma_f32_16x16x32_bf16(A10, fad, acc1, 0, 0, 0);
        acc0 = __builtin_amdgcn_mfma_f32_16x16x32_bf16(A02, fpr, acc0, 0, 0, 0);
        acc1 = __builtin_amdgcn_mfma_f32_16x16x32_bf16(A12, fpr, acc1, 0, 0, 0);
      }
      {
        const floatx4 i0v = *(const floatx4*)(xi + 32 + q * 8);
        const floatx4 i1v = *(const floatx4*)(xi + 32 + q * 8 + 4);
        float ad[8], pr[8];
#pragma unroll
        for (int t = 0; t < 4; ++t) {
          ad[t] = fabsf(i0v[t] - jB[t]);         pr[t] = i0v[t] * jB[t];
          ad[4 + t] = fabsf(i1v[t] - jB[4 + t]); pr[4 + t] = i1v[t] * jB[4 + t];
        }
        const short8 fad = pack8(ad);
        const short8 fpr = pack8(pr);
        const short8 A01 = *(const short8*)(sWt0 + c * WSTRIDE + 32 + q * 8);
        const short8 A11 = *(const short8*)(sWt0 + (16 + c) * WSTRIDE + 32 + q * 8);
        const short8 A03 = *(const short8*)(sWt0 + c * WSTRIDE + 96 + q * 8);
        const short8 A13 = *(const short8*)(sWt0 + (16 + c) * WSTRIDE + 96 + q * 8);
        acc0 = __builtin_amdgcn_mfma_f32_16x16x32_bf16(A01, fad, acc0, 0, 0, 0);
        acc1 = __builtin_amdgcn_mfma_f32_16x16x32_bf16(A11, fad, acc1, 0, 0, 0);
        acc0 = __builtin_amdgcn_mfma_f32_16x16x32_bf16(A03, fpr, acc0, 0, 0, 0);
        acc1 = __builtin_amdgcn_mfma_f32_16x16x32_bf16(A13, fpr, acc1, 0, 0, 0);
      }

      // forward: P[i][j0+c]
      float tv = 0.0f;
#pragma unroll
      for (int r = 0; r < 4; ++r) {
        tv = fmaf(fmaxf(acc0[r] + psA_i[r] + pdA_j[r], 0.0f), w2A[r], tv);
        tv = fmaf(fmaxf(acc1[r] + psB_i[r] + pdB_j[r], 0.0f), w2B[r], tv);
      }
      tv += __shfl_xor(tv, 16);
      tv += __shfl_xor(tv, 32);
      if (lane < 16) {
        outP[(size_t)i * NN + j0 + lane] = sigmoid_fast(tv + b2v);
      }

      if (offdiag) {
        const floatx4 pdA_i = *(const floatx4*)(pre + NN * HD + i * HD + q * 4);
        const floatx4 pdB_i = *(const floatx4*)(pre + NN * HD + i * HD + 16 + q * 4);
        float tm = 0.0f;
#pragma unroll
        for (int r = 0; r < 4; ++r) {
          tm = fmaf(fmaxf(acc0[r] + psA_j[r] + pdA_i[r], 0.0f), w2A[r], tm);
          tm = fmaf(fmaxf(acc1[r] + psB_j[r] + pdB_i[r], 0.0f), w2B[r], tm);
        }
        tm += __shfl_xor(tm, 16);
        tm += __shfl_xor(tm, 32);
        if (lane < 16) {
          mir[w][ii * 16 + lane] = sigmoid_fast(tm + b2v);
        }
      }
    }

    if (offdiag) {
      // coalesced mirror store: 16 rows x 64B contiguous segments
      const int r = lane >> 2;
      const int g = lane & 3;
      floatx4 v;
#pragma unroll
      for (int t = 0; t < 4; ++t) v[t] = mir[w][(4 * g + t) * 16 + r];
      *(floatx4*)(outP + (size_t)(j0 + r) * NN + i0 + 4 * g) = v;
    }
  } else {
    // ---------------- edge path: split-MFMA, fp32-accurate ----------------
    const int e0 = ((blockIdx.x - DENSE_BLOCKS) * 4 + w) * 16;

    const bool is64 = (eidx[1] == 0) && (eidx[3] == 0) && (eidx[5] == 0);
    int s_c, d_c;
    if (is64) {
      s_c = eidx[2 * (e0 + c)];
      d_c = eidx[2 * (EE + e0 + c)];
    } else {
      s_c = eidx[e0 + c];
      d_c = eidx[EE + e0 + c];
    }
    const float* xs = x + (size_t)s_c * FD;
    const float* xd = x + (size_t)d_c * FD;

    floatx4 acc0, acc1;
    {
      const floatx4 psA = *(const floatx4*)(pre + s_c * HD + q * 4);
      const floatx4 psB = *(const floatx4*)(pre + s_c * HD + 16 + q * 4);
      const floatx4 pdA = *(const floatx4*)(pre + NN * HD + d_c * HD + q * 4);
      const floatx4 pdB = *(const floatx4*)(pre + NN * HD + d_c * HD + 16 + q * 4);
#pragma unroll
      for (int r = 0; r < 4; ++r) {
        acc0[r] = psA[r] + pdA[r];
        acc1[r] = psB[r] + pdB[r];
      }
    }

    {
      const floatx4 s0 = *(const floatx4*)(xs + q * 8);
      const floatx4 s1 = *(const floatx4*)(xs + q * 8 + 4);
      const floatx4 d0 = *(const floatx4*)(xd + q * 8);
      const floatx4 d1 = *(const floatx4*)(xd + q * 8 + 4);
      float ad[8], pr[8];
#pragma unroll
      for (int t = 0; t < 4; ++t) {
        ad[t] = fabsf(s0[t] - d0[t]);     pr[t] = s0[t] * d0[t];
        ad[4 + t] = fabsf(s1[t] - d1[t]); pr[4 + t] = s1[t] * d1[t];
      }
      edge_chunk(ad, sWt0, sWt1, sWt2, c, q, 0, acc0, acc1);
      edge_chunk(pr, sWt0, sWt1, sWt2, c, q, 2, acc0, acc1);
    }
    {
      const floatx4 s0 = *(const floatx4*)(xs + 32 + q * 8);
      const floatx4 s1 = *(const floatx4*)(xs + 32 + q * 8 + 4);
      const floatx4 d0 = *(const floatx4*)(xd + 32 + q * 8);
      const floatx4 d1 = *(const floatx4*)(xd + 32 + q * 8 + 4);
      float ad[8], pr[8];
#pragma unroll
      for (int t = 0; t < 4; ++t) {
        ad[t] = fabsf(s0[t] - d0[t]);     pr[t] = s0[t] * d0[t];
        ad[4 + t] = fabsf(s1[t] - d1[t]); pr[4 + t] = s1[t] * d1[t];
      }
      edge_chunk(ad, sWt0, sWt1, sWt2, c, q, 1, acc0, acc1);
      edge_chunk(pr, sWt0, sWt1, sWt2, c, q, 3, acc0, acc1);
    }

    const floatx4 w2A = *(const floatx4*)(W2 + q * 4);
    const floatx4 w2B = *(const floatx4*)(W2 + 16 + q * 4);
    float tv = 0.0f;
#pragma unroll
    for (int r = 0; r < 4; ++r) {
      tv = fmaf(fmaxf(acc0[r], 0.0f), w2A[r], tv);
      tv = fmaf(fmaxf(acc1[r], 0.0f), w2B[r], tv);
    }
    tv += __shfl_xor(tv, 16);
    tv += __shfl_xor(tv, 32);
    if (lane < 16) {
      const int e = e0 + lane;
      const float z = tv + b2[0];
      out[e] = sigmoid_f(z);
      out[EE + e] = (z > -0.40546510810816444f) ? 1.0f : 0.0f;
    }
  }
}

// ---------------------------------------------------------------------------
// Fallbacks (no-workspace path)
// ---------------------------------------------------------------------------
__device__ __forceinline__ float pair_logit_full(
    const float* __restrict__ xs, const float* __restrict__ xd,
    const float* __restrict__ W1, const float* __restrict__ b1,
    const float* __restrict__ W2, const float b2v) {
  float acc[HD];
#pragma unroll
  for (int h = 0; h < HD; ++h) acc[h] = b1[h];
#pragma unroll 1
  for (int f = 0; f < FD; ++f) {
    const float a = xs[f], b = xd[f];
    const float ad = fabsf(a - b), pr = a * b;
#pragma unroll
    for (int h = 0; h < HD; ++h) {
      float t0 = fmaf(a, W1[f * HD + h], acc[h]);
      t0 = fmaf(b, W1[(FD + f) * HD + h], t0);
      t0 = fmaf(ad, W1[(2 * FD + f) * HD + h], t0);
      acc[h] = fmaf(pr, W1[(3 * FD + f) * HD + h], t0);
    }
  }
  float z = b2v;
#pragma unroll
  for (int h = 0; h < HD; ++h) z = fmaf(fmaxf(acc[h], 0.0f), W2[h], z);
  return z;
}

__global__ __launch_bounds__(256) void edge_kernel_fb(
    const float* __restrict__ x, const int* __restrict__ eidx,
    const float* __restrict__ W1, const float* __restrict__ b1,
    const float* __restrict__ W2, const float* __restrict__ b2,
    float* __restrict__ out) {
  const int e = blockIdx.x * 256 + threadIdx.x;
  const bool is64 = (eidx[1] == 0) && (eidx[3] == 0) && (eidx[5] == 0);
  int s, d;
  if (is64) { s = eidx[2 * e]; d = eidx[2 * (EE + e)]; }
  else { s = eidx[e]; d = eidx[EE + e]; }
  const float z = pair_logit_full(x + (size_t)s * FD, x + (size_t)d * FD,
                                  W1, b1, W2, b2[0]);
  const float p = sigmoid_f(z);
  out[e] = p;
  out[EE + e] = (p > 0.4f) ? 1.0f : 0.0f;
}

__global__ __launch_bounds__(256) void dense_full_fb(
    const float* __restrict__ x, const float* __restrict__ W1,
    const float* __restrict__ b1, const float* __restrict__ W2,
    const float* __restrict__ b2, float* __restrict__ outP) {
  const int j = blockIdx.x * 64 + threadIdx.x % 64;
  const int i = blockIdx.y * 4 + threadIdx.x / 64;
  const float z = pair_logit_full(x + (size_t)i * FD, x + (size_t)j * FD,
                                  W1, b1, W2, b2[0]);
  outP[(size_t)i * NN + j] = sigmoid_f(z);
}

extern "C" void kernel_launch(void* const* d_in, const int* in_sizes, int n_in,
                              void* d_out, int out_size, void* d_ws, size_t ws_size,
                              hipStream_t stream) {
  const float* x  = (const float*)d_in[0];
  const int*  ei  = (const int*)d_in[1];
  const float* W1 = (const float*)d_in[3];
  const float* b1 = (const float*)d_in[4];
  const float* W2 = (const float*)d_in[5];
  const float* b2 = (const float*)d_in[6];
  float* out  = (float*)d_out;   // [0,EE) probs, [EE,2EE) actions
  float* outP = out + 2 * EE;    // [2EE, 2EE+NN*NN) P

  const size_t pre_bytes = (size_t)2 * NN * HD * sizeof(float);
  const size_t wt_elems = 32 * 128;
  const size_t need = pre_bytes + 3 * wt_elems * sizeof(short);
  if (ws_size >= need) {
    float* pre = (float*)d_ws;
    short* Wt0 = (short*)((char*)d_ws + pre_bytes);
    short* Wt1 = Wt0 + wt_elems;
    short* Wt2 = Wt1 + wt_elems;
    pre_kernel3<<<257, 256, 0, stream>>>(x, W1, b1, pre, Wt0, Wt1, Wt2);
    fused_mfma_kernel<<<DENSE_BLOCKS + 1024, 256, 0, stream>>>(
        x, ei, pre, Wt0, Wt1, Wt2, W2, b2, out, outP);
  } else {
    edge_kernel_fb<<<EE / 256, 256, 0, stream>>>(x, ei, W1, b1, W2, b2, out);
    dense_full_fb<<<dim3(NN / 64, NN / 4), 256, 0, stream>>>(
        x, W1, b1, W2, b2, outP);
  }
}

// Round 13
// 97.486 us; speedup vs baseline: 1.1137x; 1.1137x over previous
//
#include <hip/hip_runtime.h>
#include <hip/hip_bf16.h>
#include <math.h>

#define NN 1024   // nodes
#define FD 64     // features
#define EE 65536  // edges
#define HD 32     // hidden

typedef __attribute__((ext_vector_type(8))) short short8;
typedef __attribute__((ext_vector_type(4))) float floatx4;

__device__ __forceinline__ float sigmoid_f(float z) {
  return 1.0f / (1.0f + expf(-z));
}
__device__ __forceinline__ float sigmoid_fast(float z) {
  return 1.0f / (1.0f + __expf(-z));
}

__device__ __forceinline__ unsigned pack_bf16_trunc(float hi, float lo) {
  unsigned a = __builtin_bit_cast(unsigned, hi);
  unsigned b = __builtin_bit_cast(unsigned, lo);
  return __builtin_amdgcn_perm(a, b, 0x07060302u);
}

__device__ __forceinline__ short8 pack8(const float* v) {
  union { unsigned u[4]; short8 s; } p;
#pragma unroll
  for (int t = 0; t < 4; ++t) p.u[t] = pack_bf16_trunc(v[2 * t + 1], v[2 * t]);
  return p.s;
}

struct Frag3 { short8 a0, a1, a2; };

// 3-way bf16 split (exact: 8+8+8 mantissa bits) of 8 fp32 values.
__device__ __forceinline__ Frag3 split_pack(const float* v) {
  float r[8], r2[8];
#pragma unroll
  for (int t = 0; t < 8; ++t) {
    const unsigned uv = __builtin_bit_cast(unsigned, v[t]);
    const float f0 = __builtin_bit_cast(float, uv & 0xFFFF0000u);
    const float rr = v[t] - f0;
    const unsigned ur = __builtin_bit_cast(unsigned, rr);
    const float f1 = __builtin_bit_cast(float, ur & 0xFFFF0000u);
    r[t] = rr;
    r2[t] = rr - f1;
  }
  Frag3 f;
  f.a0 = pack8(v);
  f.a1 = pack8(r);
  f.a2 = pack8(r2);
  return f;
}

// ---------------------------------------------------------------------------
// Pre-pass: pre[which][node][h]; block 256 builds Wt0/1/2 splits.
// ---------------------------------------------------------------------------
__global__ __launch_bounds__(256) void pre_kernel3(
    const float* __restrict__ x, const float* __restrict__ W1,
    const float* __restrict__ b1, float* __restrict__ pre,
    short* __restrict__ Wt0, short* __restrict__ Wt1, short* __restrict__ Wt2) {
  const int blk = blockIdx.x;
  const int t = threadIdx.x;
  if (blk < 256) {
    const int node = blk * 4 + (t >> 6);
    const int which = (t >> 5) & 1;
    const int h = t & 31;
    const float* xr = x + node * FD;
    const float* wp = W1 + which * FD * HD + h;
    float a0 = which ? 0.0f : b1[h], a1 = 0.0f, a2 = 0.0f, a3 = 0.0f;
#pragma unroll
    for (int f = 0; f < FD; f += 4) {
      a0 = fmaf(xr[f + 0], wp[(f + 0) * HD], a0);
      a1 = fmaf(xr[f + 1], wp[(f + 1) * HD], a1);
      a2 = fmaf(xr[f + 2], wp[(f + 2) * HD], a2);
      a3 = fmaf(xr[f + 3], wp[(f + 3) * HD], a3);
    }
    pre[which * (NN * HD) + node * HD + h] = (a0 + a1) + (a2 + a3);
  } else {
    for (int idx = t; idx < 32 * 128; idx += 256) {
      const int h = idx >> 7;
      const int k = idx & 127;
      const int f = k & 63;
      const int b = 2 + (k >> 6);
      const float v = W1[(b * FD + f) * HD + h];
      const unsigned uv = __builtin_bit_cast(unsigned, v);
      const unsigned u0 = uv & 0xFFFF0000u;
      const float f0 = __builtin_bit_cast(float, u0);
      const float r = v - f0;
      const unsigned u1 = __builtin_bit_cast(unsigned, r) & 0xFFFF0000u;
      const float f1 = __builtin_bit_cast(float, u1);
      const float r2 = r - f1;
      const unsigned u2 = __builtin_bit_cast(unsigned, r2) & 0xFFFF0000u;
      Wt0[idx] = (short)(u0 >> 16);
      Wt1[idx] = (short)(u1 >> 16);
      Wt2[idx] = (short)(u2 >> 16);
    }
  }
}

// ---------------------------------------------------------------------------
// Edge helper: 12 split-MFMAs for one 8-feature chunk. A-frags from LDS,
// fragment-major layout: sW[fid*64 + lane], fid = kc*2 + n.
// ---------------------------------------------------------------------------
__device__ __forceinline__ void edge_chunk(
    const float* feat, const short8* sW0, const short8* sW1, const short8* sW2,
    int lane, int kc, floatx4& acc0, floatx4& acc1) {
  const Frag3 B = split_pack(feat);
  const int f0 = (kc * 2 + 0) * 64 + lane;
  const int f1 = (kc * 2 + 1) * 64 + lane;
  const short8 A00 = sW0[f0];
  const short8 A01 = sW1[f0];
  const short8 A02 = sW2[f0];
  const short8 A10 = sW0[f1];
  const short8 A11 = sW1[f1];
  const short8 A12 = sW2[f1];
  acc0 = __builtin_amdgcn_mfma_f32_16x16x32_bf16(A00, B.a0, acc0, 0, 0, 0);
  acc0 = __builtin_amdgcn_mfma_f32_16x16x32_bf16(A01, B.a0, acc0, 0, 0, 0);
  acc0 = __builtin_amdgcn_mfma_f32_16x16x32_bf16(A02, B.a0, acc0, 0, 0, 0);
  acc0 = __builtin_amdgcn_mfma_f32_16x16x32_bf16(A00, B.a1, acc0, 0, 0, 0);
  acc0 = __builtin_amdgcn_mfma_f32_16x16x32_bf16(A01, B.a1, acc0, 0, 0, 0);
  acc0 = __builtin_amdgcn_mfma_f32_16x16x32_bf16(A00, B.a2, acc0, 0, 0, 0);
  acc1 = __builtin_amdgcn_mfma_f32_16x16x32_bf16(A10, B.a0, acc1, 0, 0, 0);
  acc1 = __builtin_amdgcn_mfma_f32_16x16x32_bf16(A11, B.a0, acc1, 0, 0, 0);
  acc1 = __builtin_amdgcn_mfma_f32_16x16x32_bf16(A12, B.a0, acc1, 0, 0, 0);
  acc1 = __builtin_amdgcn_mfma_f32_16x16x32_bf16(A10, B.a1, acc1, 0, 0, 0);
  acc1 = __builtin_amdgcn_mfma_f32_16x16x32_bf16(A11, B.a1, acc1, 0, 0, 0);
  acc1 = __builtin_amdgcn_mfma_f32_16x16x32_bf16(A10, B.a2, acc1, 0, 0, 0);
}

// ---------------------------------------------------------------------------
// Fused edge+dense kernel (R11 config). Wt in LDS, FRAGMENT-MAJOR layout:
// lane i's 16B fragment at (fid*64+i)*16 bytes -> every wave ds_read_b128 /
// ds_write_b128 touches 64 consecutive 16B chunks = conflict-free (R12
// counter showed 508K conflicts from the padded-matrix layout's 8-way
// aliasing: stride 68 dwords == 4 mod 32).
// ---------------------------------------------------------------------------
#define DENSE_BLOCKS 520

__global__ __launch_bounds__(256, 2) void fused_mfma_kernel(
    const float* __restrict__ x, const int* __restrict__ eidx,
    const float* __restrict__ pre, const short* __restrict__ Wt0,
    const short* __restrict__ Wt1, const short* __restrict__ Wt2,
    const float* __restrict__ W2, const float* __restrict__ b2,
    float* __restrict__ out, float* __restrict__ outP) {
  __shared__ short8 sW0[512];  // [fid=kc*2+n][lane]  8 KB
  __shared__ short8 sW1[512];
  __shared__ short8 sW2[512];
  __shared__ float mir[4][256];

  // ---- stage Wt into LDS, pre-swizzled to fragment-major ----
  for (int idx = threadIdx.x; idx < 512; idx += 256) {
    const int fid = idx >> 6;
    const int ln = idx & 63;
    const int lq = ln >> 4;
    const int lc = ln & 15;
    const int kc = fid >> 1;
    const int n = fid & 1;
    const int src = (n * 16 + lc) * 128 + kc * 32 + lq * 8;
    sW0[idx] = *(const short8*)(Wt0 + src);
    sW1[idx] = *(const short8*)(Wt1 + src);
    sW2[idx] = *(const short8*)(Wt2 + src);
  }
  __syncthreads();

  const int lane = threadIdx.x & 63;
  const int w = threadIdx.x >> 6;
  const int q = lane >> 4;
  const int c = lane & 15;

  if (blockIdx.x < DENSE_BLOCKS) {
    // ---------------- dense path: symmetric bilinear, triangular tiling ----
    const int T = blockIdx.x * 4 + w;
    int a = (int)((sqrtf(8.0f * (float)T + 1.0f) - 1.0f) * 0.5f);
    while ((a + 1) * (a + 2) / 2 <= T) ++a;
    while (a * (a + 1) / 2 > T) --a;
    const int b = T - a * (a + 1) / 2;
    const int j0 = a * 16;
    const int i0 = b * 16;
    const bool offdiag = (a != b);

    const float* xj = x + (size_t)(j0 + c) * FD;
    float jA[8], jB[8];
#pragma unroll
    for (int t = 0; t < 4; ++t) {
      jA[t] = xj[q * 8 + t];      jA[4 + t] = xj[q * 8 + 4 + t];
      jB[t] = xj[32 + q * 8 + t]; jB[4 + t] = xj[32 + q * 8 + 4 + t];
    }

    const floatx4 psA_j = *(const floatx4*)(pre + (j0 + c) * HD + q * 4);
    const floatx4 psB_j = *(const floatx4*)(pre + (j0 + c) * HD + 16 + q * 4);
    const floatx4 pdA_j = *(const floatx4*)(pre + NN * HD + (j0 + c) * HD + q * 4);
    const floatx4 pdB_j = *(const floatx4*)(pre + NN * HD + (j0 + c) * HD + 16 + q * 4);
    const floatx4 w2A = *(const floatx4*)(W2 + q * 4);
    const floatx4 w2B = *(const floatx4*)(W2 + 16 + q * 4);
    const float b2v = b2[0];

    for (int ii = 0; ii < 16; ++ii) {
      const int i = i0 + ii;
      const float* xi = x + (size_t)i * FD;
      const floatx4 psA_i = *(const floatx4*)(pre + i * HD + q * 4);
      const floatx4 psB_i = *(const floatx4*)(pre + i * HD + 16 + q * 4);
      floatx4 acc0 = {0.0f, 0.0f, 0.0f, 0.0f};
      floatx4 acc1 = {0.0f, 0.0f, 0.0f, 0.0f};

      {
        const floatx4 i0v = *(const floatx4*)(xi + q * 8);
        const floatx4 i1v = *(const floatx4*)(xi + q * 8 + 4);
        float ad[8], pr[8];
#pragma unroll
        for (int t = 0; t < 4; ++t) {
          ad[t] = fabsf(i0v[t] - jA[t]);         pr[t] = i0v[t] * jA[t];
          ad[4 + t] = fabsf(i1v[t] - jA[4 + t]); pr[4 + t] = i1v[t] * jA[4 + t];
        }
        const short8 fad = pack8(ad);
        const short8 fpr = pack8(pr);
        const short8 A00 = sW0[0 * 64 + lane];   // kc=0, n=0
        const short8 A10 = sW0[1 * 64 + lane];   // kc=0, n=1
        const short8 A02 = sW0[4 * 64 + lane];   // kc=2, n=0
        const short8 A12 = sW0[5 * 64 + lane];   // kc=2, n=1
        acc0 = __builtin_amdgcn_mfma_f32_16x16x32_bf16(A00, fad, acc0, 0, 0, 0);
        acc1 = __builtin_amdgcn_mfma_f32_16x16x32_bf16(A10, fad, acc1, 0, 0, 0);
        acc0 = __builtin_amdgcn_mfma_f32_16x16x32_bf16(A02, fpr, acc0, 0, 0, 0);
        acc1 = __builtin_amdgcn_mfma_f32_16x16x32_bf16(A12, fpr, acc1, 0, 0, 0);
      }
      {
        const floatx4 i0v = *(const floatx4*)(xi + 32 + q * 8);
        const floatx4 i1v = *(const floatx4*)(xi + 32 + q * 8 + 4);
        float ad[8], pr[8];
#pragma unroll
        for (int t = 0; t < 4; ++t) {
          ad[t] = fabsf(i0v[t] - jB[t]);         pr[t] = i0v[t] * jB[t];
          ad[4 + t] = fabsf(i1v[t] - jB[4 + t]); pr[4 + t] = i1v[t] * jB[4 + t];
        }
        const short8 fad = pack8(ad);
        const short8 fpr = pack8(pr);
        const short8 A01 = sW0[2 * 64 + lane];   // kc=1, n=0
        const short8 A11 = sW0[3 * 64 + lane];   // kc=1, n=1
        const short8 A03 = sW0[6 * 64 + lane];   // kc=3, n=0
        const short8 A13 = sW0[7 * 64 + lane];   // kc=3, n=1
        acc0 = __builtin_amdgcn_mfma_f32_16x16x32_bf16(A01, fad, acc0, 0, 0, 0);
        acc1 = __builtin_amdgcn_mfma_f32_16x16x32_bf16(A11, fad, acc1, 0, 0, 0);
        acc0 = __builtin_amdgcn_mfma_f32_16x16x32_bf16(A03, fpr, acc0, 0, 0, 0);
        acc1 = __builtin_amdgcn_mfma_f32_16x16x32_bf16(A13, fpr, acc1, 0, 0, 0);
      }

      // forward: P[i][j0+c]
      float tv = 0.0f;
#pragma unroll
      for (int r = 0; r < 4; ++r) {
        tv = fmaf(fmaxf(acc0[r] + psA_i[r] + pdA_j[r], 0.0f), w2A[r], tv);
        tv = fmaf(fmaxf(acc1[r] + psB_i[r] + pdB_j[r], 0.0f), w2B[r], tv);
      }
      tv += __shfl_xor(tv, 16);
      tv += __shfl_xor(tv, 32);
      if (lane < 16) {
        outP[(size_t)i * NN + j0 + lane] = sigmoid_fast(tv + b2v);
      }

      if (offdiag) {
        const floatx4 pdA_i = *(const floatx4*)(pre + NN * HD + i * HD + q * 4);
        const floatx4 pdB_i = *(const floatx4*)(pre + NN * HD + i * HD + 16 + q * 4);
        float tm = 0.0f;
#pragma unroll
        for (int r = 0; r < 4; ++r) {
          tm = fmaf(fmaxf(acc0[r] + psA_j[r] + pdA_i[r], 0.0f), w2A[r], tm);
          tm = fmaf(fmaxf(acc1[r] + psB_j[r] + pdB_i[r], 0.0f), w2B[r], tm);
        }
        tm += __shfl_xor(tm, 16);
        tm += __shfl_xor(tm, 32);
        if (lane < 16) {
          mir[w][ii * 16 + lane] = sigmoid_fast(tm + b2v);
        }
      }
    }

    if (offdiag) {
      // coalesced mirror store: 16 rows x 64B contiguous segments
      const int r = lane >> 2;
      const int g = lane & 3;
      floatx4 v;
#pragma unroll
      for (int t = 0; t < 4; ++t) v[t] = mir[w][(4 * g + t) * 16 + r];
      *(floatx4*)(outP + (size_t)(j0 + r) * NN + i0 + 4 * g) = v;
    }
  } else {
    // ---------------- edge path: split-MFMA, fp32-accurate ----------------
    const int e0 = ((blockIdx.x - DENSE_BLOCKS) * 4 + w) * 16;

    const bool is64 = (eidx[1] == 0) && (eidx[3] == 0) && (eidx[5] == 0);
    int s_c, d_c;
    if (is64) {
      s_c = eidx[2 * (e0 + c)];
      d_c = eidx[2 * (EE + e0 + c)];
    } else {
      s_c = eidx[e0 + c];
      d_c = eidx[EE + e0 + c];
    }
    const float* xs = x + (size_t)s_c * FD;
    const float* xd = x + (size_t)d_c * FD;

    floatx4 acc0, acc1;
    {
      const floatx4 psA = *(const floatx4*)(pre + s_c * HD + q * 4);
      const floatx4 psB = *(const floatx4*)(pre + s_c * HD + 16 + q * 4);
      const floatx4 pdA = *(const floatx4*)(pre + NN * HD + d_c * HD + q * 4);
      const floatx4 pdB = *(const floatx4*)(pre + NN * HD + d_c * HD + 16 + q * 4);
#pragma unroll
      for (int r = 0; r < 4; ++r) {
        acc0[r] = psA[r] + pdA[r];
        acc1[r] = psB[r] + pdB[r];
      }
    }

    {
      const floatx4 s0 = *(const floatx4*)(xs + q * 8);
      const floatx4 s1 = *(const floatx4*)(xs + q * 8 + 4);
      const floatx4 d0 = *(const floatx4*)(xd + q * 8);
      const floatx4 d1 = *(const floatx4*)(xd + q * 8 + 4);
      float ad[8], pr[8];
#pragma unroll
      for (int t = 0; t < 4; ++t) {
        ad[t] = fabsf(s0[t] - d0[t]);     pr[t] = s0[t] * d0[t];
        ad[4 + t] = fabsf(s1[t] - d1[t]); pr[4 + t] = s1[t] * d1[t];
      }
      edge_chunk(ad, sW0, sW1, sW2, lane, 0, acc0, acc1);
      edge_chunk(pr, sW0, sW1, sW2, lane, 2, acc0, acc1);
    }
    {
      const floatx4 s0 = *(const floatx4*)(xs + 32 + q * 8);
      const floatx4 s1 = *(const floatx4*)(xs + 32 + q * 8 + 4);
      const floatx4 d0 = *(const floatx4*)(xd + 32 + q * 8);
      const floatx4 d1 = *(const floatx4*)(xd + 32 + q * 8 + 4);
      float ad[8], pr[8];
#pragma unroll
      for (int t = 0; t < 4; ++t) {
        ad[t] = fabsf(s0[t] - d0[t]);     pr[t] = s0[t] * d0[t];
        ad[4 + t] = fabsf(s1[t] - d1[t]); pr[4 + t] = s1[t] * d1[t];
      }
      edge_chunk(ad, sW0, sW1, sW2, lane, 1, acc0, acc1);
      edge_chunk(pr, sW0, sW1, sW2, lane, 3, acc0, acc1);
    }

    const floatx4 w2A = *(const floatx4*)(W2 + q * 4);
    const floatx4 w2B = *(const floatx4*)(W2 + 16 + q * 4);
    float tv = 0.0f;
#pragma unroll
    for (int r = 0; r < 4; ++r) {
      tv = fmaf(fmaxf(acc0[r], 0.0f), w2A[r], tv);
      tv = fmaf(fmaxf(acc1[r], 0.0f), w2B[r], tv);
    }
    tv += __shfl_xor(tv, 16);
    tv += __shfl_xor(tv, 32);
    if (lane < 16) {
      const int e = e0 + lane;
      const float z = tv + b2[0];
      out[e] = sigmoid_f(z);
      out[EE + e] = (z > -0.40546510810816444f) ? 1.0f : 0.0f;
    }
  }
}

// ---------------------------------------------------------------------------
// Fallbacks (no-workspace path)
// ---------------------------------------------------------------------------
__device__ __forceinline__ float pair_logit_full(
    const float* __restrict__ xs, const float* __restrict__ xd,
    const float* __restrict__ W1, const float* __restrict__ b1,
    const float* __restrict__ W2, const float b2v) {
  float acc[HD];
#pragma unroll
  for (int h = 0; h < HD; ++h) acc[h] = b1[h];
#pragma unroll 1
  for (int f = 0; f < FD; ++f) {
    const float a = xs[f], b = xd[f];
    const float ad = fabsf(a - b), pr = a * b;
#pragma unroll
    for (int h = 0; h < HD; ++h) {
      float t0 = fmaf(a, W1[f * HD + h], acc[h]);
      t0 = fmaf(b, W1[(FD + f) * HD + h], t0);
      t0 = fmaf(ad, W1[(2 * FD + f) * HD + h], t0);
      acc[h] = fmaf(pr, W1[(3 * FD + f) * HD + h], t0);
    }
  }
  float z = b2v;
#pragma unroll
  for (int h = 0; h < HD; ++h) z = fmaf(fmaxf(acc[h], 0.0f), W2[h], z);
  return z;
}

__global__ __launch_bounds__(256) void edge_kernel_fb(
    const float* __restrict__ x, const int* __restrict__ eidx,
    const float* __restrict__ W1, const float* __restrict__ b1,
    const float* __restrict__ W2, const float* __restrict__ b2,
    float* __restrict__ out) {
  const int e = blockIdx.x * 256 + threadIdx.x;
  const bool is64 = (eidx[1] == 0) && (eidx[3] == 0) && (eidx[5] == 0);
  int s, d;
  if (is64) { s = eidx[2 * e]; d = eidx[2 * (EE + e)]; }
  else { s = eidx[e]; d = eidx[EE + e]; }
  const float z = pair_logit_full(x + (size_t)s * FD, x + (size_t)d * FD,
                                  W1, b1, W2, b2[0]);
  const float p = sigmoid_f(z);
  out[e] = p;
  out[EE + e] = (p > 0.4f) ? 1.0f : 0.0f;
}

__global__ __launch_bounds__(256) void dense_full_fb(
    const float* __restrict__ x, const float* __restrict__ W1,
    const float* __restrict__ b1, const float* __restrict__ W2,
    const float* __restrict__ b2, float* __restrict__ outP) {
  const int j = blockIdx.x * 64 + threadIdx.x % 64;
  const int i = blockIdx.y * 4 + threadIdx.x / 64;
  const float z = pair_logit_full(x + (size_t)i * FD, x + (size_t)j * FD,
                                  W1, b1, W2, b2[0]);
  outP[(size_t)i * NN + j] = sigmoid_f(z);
}

extern "C" void kernel_launch(void* const* d_in, const int* in_sizes, int n_in,
                              void* d_out, int out_size, void* d_ws, size_t ws_size,
                              hipStream_t stream) {
  const float* x  = (const float*)d_in[0];
  const int*  ei  = (const int*)d_in[1];
  const float* W1 = (const float*)d_in[3];
  const float* b1 = (const float*)d_in[4];
  const float* W2 = (const float*)d_in[5];
  const float* b2 = (const float*)d_in[6];
  float* out  = (float*)d_out;   // [0,EE) probs, [EE,2EE) actions
  float* outP = out + 2 * EE;    // [2EE, 2EE+NN*NN) P

  const size_t pre_bytes = (size_t)2 * NN * HD * sizeof(float);
  const size_t wt_elems = 32 * 128;
  const size_t need = pre_bytes + 3 * wt_elems * sizeof(short);
  if (ws_size >= need) {
    float* pre = (float*)d_ws;
    short* Wt0 = (short*)((char*)d_ws + pre_bytes);
    short* Wt1 = Wt0 + wt_elems;
    short* Wt2 = Wt1 + wt_elems;
    pre_kernel3<<<257, 256, 0, stream>>>(x, W1, b1, pre, Wt0, Wt1, Wt2);
    fused_mfma_kernel<<<DENSE_BLOCKS + 1024, 256, 0, stream>>>(
        x, ei, pre, Wt0, Wt1, Wt2, W2, b2, out, outP);
  } else {
    edge_kernel_fb<<<EE / 256, 256, 0, stream>>>(x, ei, W1, b1, W2, b2, out);
    dense_full_fb<<<dim3(NN / 64, NN / 4), 256, 0, stream>>>(
        x, W1, b1, W2, b2, outP);
  }
}

// Round 14
// 94.880 us; speedup vs baseline: 1.1443x; 1.0275x over previous
//
#include <hip/hip_runtime.h>
#include <hip/hip_bf16.h>
#include <math.h>

#define NN 1024   // nodes
#define FD 64     // features
#define EE 65536  // edges
#define HD 32     // hidden
#define WSTRIDE 136  // LDS row stride in shorts (128 + 8 pad)

typedef __attribute__((ext_vector_type(8))) short short8;
typedef __attribute__((ext_vector_type(4))) float floatx4;

__device__ __forceinline__ float sigmoid_f(float z) {
  return 1.0f / (1.0f + expf(-z));
}
__device__ __forceinline__ float sigmoid_fast(float z) {
  return 1.0f / (1.0f + __expf(-z));
}

__device__ __forceinline__ unsigned pack_bf16_trunc(float hi, float lo) {
  unsigned a = __builtin_bit_cast(unsigned, hi);
  unsigned b = __builtin_bit_cast(unsigned, lo);
  return __builtin_amdgcn_perm(a, b, 0x07060302u);
}

__device__ __forceinline__ short8 pack8(const float* v) {
  union { unsigned u[4]; short8 s; } p;
#pragma unroll
  for (int t = 0; t < 4; ++t) p.u[t] = pack_bf16_trunc(v[2 * t + 1], v[2 * t]);
  return p.s;
}

struct Frag3 { short8 a0, a1, a2; };

// 3-way bf16 split (exact: 8+8+8 mantissa bits) of 8 fp32 values.
__device__ __forceinline__ Frag3 split_pack(const float* v) {
  float r[8], r2[8];
#pragma unroll
  for (int t = 0; t < 8; ++t) {
    const unsigned uv = __builtin_bit_cast(unsigned, v[t]);
    const float f0 = __builtin_bit_cast(float, uv & 0xFFFF0000u);
    const float rr = v[t] - f0;
    const unsigned ur = __builtin_bit_cast(unsigned, rr);
    const float f1 = __builtin_bit_cast(float, ur & 0xFFFF0000u);
    r[t] = rr;
    r2[t] = rr - f1;
  }
  Frag3 f;
  f.a0 = pack8(v);
  f.a1 = pack8(r);
  f.a2 = pack8(r2);
  return f;
}

// ---------------------------------------------------------------------------
// Pre-pass: pre[which][node][h]; block 256 builds Wt0/1/2 splits.
// ---------------------------------------------------------------------------
__global__ __launch_bounds__(256) void pre_kernel3(
    const float* __restrict__ x, const float* __restrict__ W1,
    const float* __restrict__ b1, float* __restrict__ pre,
    short* __restrict__ Wt0, short* __restrict__ Wt1, short* __restrict__ Wt2) {
  const int blk = blockIdx.x;
  const int t = threadIdx.x;
  if (blk < 256) {
    const int node = blk * 4 + (t >> 6);
    const int which = (t >> 5) & 1;
    const int h = t & 31;
    const float* xr = x + node * FD;
    const float* wp = W1 + which * FD * HD + h;
    float a0 = which ? 0.0f : b1[h], a1 = 0.0f, a2 = 0.0f, a3 = 0.0f;
#pragma unroll
    for (int f = 0; f < FD; f += 4) {
      a0 = fmaf(xr[f + 0], wp[(f + 0) * HD], a0);
      a1 = fmaf(xr[f + 1], wp[(f + 1) * HD], a1);
      a2 = fmaf(xr[f + 2], wp[(f + 2) * HD], a2);
      a3 = fmaf(xr[f + 3], wp[(f + 3) * HD], a3);
    }
    pre[which * (NN * HD) + node * HD + h] = (a0 + a1) + (a2 + a3);
  } else {
    for (int idx = t; idx < 32 * 128; idx += 256) {
      const int h = idx >> 7;
      const int k = idx & 127;
      const int f = k & 63;
      const int b = 2 + (k >> 6);
      const float v = W1[(b * FD + f) * HD + h];
      const unsigned uv = __builtin_bit_cast(unsigned, v);
      const unsigned u0 = uv & 0xFFFF0000u;
      const float f0 = __builtin_bit_cast(float, u0);
      const float r = v - f0;
      const unsigned u1 = __builtin_bit_cast(unsigned, r) & 0xFFFF0000u;
      const float f1 = __builtin_bit_cast(float, u1);
      const float r2 = r - f1;
      const unsigned u2 = __builtin_bit_cast(unsigned, r2) & 0xFFFF0000u;
      Wt0[idx] = (short)(u0 >> 16);
      Wt1[idx] = (short)(u1 >> 16);
      Wt2[idx] = (short)(u2 >> 16);
    }
  }
}

// ---------------------------------------------------------------------------
// Edge helper: 12 split-MFMAs for one 8-feature chunk. A-frags from LDS.
// ---------------------------------------------------------------------------
__device__ __forceinline__ void edge_chunk(
    const float* feat, const short* sWt0, const short* sWt1, const short* sWt2,
    int c, int q, int kc, floatx4& acc0, floatx4& acc1) {
  const Frag3 B = split_pack(feat);
  const int off0 = c * WSTRIDE + kc * 32 + q * 8;
  const int off1 = (16 + c) * WSTRIDE + kc * 32 + q * 8;
  const short8 A00 = *(const short8*)(sWt0 + off0);
  const short8 A01 = *(const short8*)(sWt1 + off0);
  const short8 A02 = *(const short8*)(sWt2 + off0);
  const short8 A10 = *(const short8*)(sWt0 + off1);
  const short8 A11 = *(const short8*)(sWt1 + off1);
  const short8 A12 = *(const short8*)(sWt2 + off1);
  acc0 = __builtin_amdgcn_mfma_f32_16x16x32_bf16(A00, B.a0, acc0, 0, 0, 0);
  acc0 = __builtin_amdgcn_mfma_f32_16x16x32_bf16(A01, B.a0, acc0, 0, 0, 0);
  acc0 = __builtin_amdgcn_mfma_f32_16x16x32_bf16(A02, B.a0, acc0, 0, 0, 0);
  acc0 = __builtin_amdgcn_mfma_f32_16x16x32_bf16(A00, B.a1, acc0, 0, 0, 0);
  acc0 = __builtin_amdgcn_mfma_f32_16x16x32_bf16(A01, B.a1, acc0, 0, 0, 0);
  acc0 = __builtin_amdgcn_mfma_f32_16x16x32_bf16(A00, B.a2, acc0, 0, 0, 0);
  acc1 = __builtin_amdgcn_mfma_f32_16x16x32_bf16(A10, B.a0, acc1, 0, 0, 0);
  acc1 = __builtin_amdgcn_mfma_f32_16x16x32_bf16(A11, B.a0, acc1, 0, 0, 0);
  acc1 = __builtin_amdgcn_mfma_f32_16x16x32_bf16(A12, B.a0, acc1, 0, 0, 0);
  acc1 = __builtin_amdgcn_mfma_f32_16x16x32_bf16(A10, B.a1, acc1, 0, 0, 0);
  acc1 = __builtin_amdgcn_mfma_f32_16x16x32_bf16(A11, B.a1, acc1, 0, 0, 0);
  acc1 = __builtin_amdgcn_mfma_f32_16x16x32_bf16(A10, B.a2, acc1, 0, 0, 0);
}

// ---------------------------------------------------------------------------
// Fused edge+dense kernel (R11 exact — measured best, 94.0 us total).
// Wt staged in LDS: the allocator's low-VGPR rematerialization re-reads
// LDS (~12 cyc) instead of L2 (~200-300 cyc) per fragment.
// ---------------------------------------------------------------------------
#define DENSE_BLOCKS 520

__global__ __launch_bounds__(256, 2) void fused_mfma_kernel(
    const float* __restrict__ x, const int* __restrict__ eidx,
    const float* __restrict__ pre, const short* __restrict__ Wt0,
    const short* __restrict__ Wt1, const short* __restrict__ Wt2,
    const float* __restrict__ W2, const float* __restrict__ b2,
    float* __restrict__ out, float* __restrict__ outP) {
  __shared__ short sWt0[32 * WSTRIDE];
  __shared__ short sWt1[32 * WSTRIDE];
  __shared__ short sWt2[32 * WSTRIDE];
  __shared__ float mir[4][256];

  // ---- stage Wt into LDS (vectorized, one-time) ----
  for (int idx = threadIdx.x; idx < 512; idx += 256) {
    const int h = idx >> 4;
    const int kk = (idx & 15) * 8;
    *(short8*)(sWt0 + h * WSTRIDE + kk) = *(const short8*)(Wt0 + h * 128 + kk);
    *(short8*)(sWt1 + h * WSTRIDE + kk) = *(const short8*)(Wt1 + h * 128 + kk);
    *(short8*)(sWt2 + h * WSTRIDE + kk) = *(const short8*)(Wt2 + h * 128 + kk);
  }
  __syncthreads();

  const int lane = threadIdx.x & 63;
  const int w = threadIdx.x >> 6;
  const int q = lane >> 4;
  const int c = lane & 15;

  if (blockIdx.x < DENSE_BLOCKS) {
    // ---------------- dense path: symmetric bilinear, triangular tiling ----
    const int T = blockIdx.x * 4 + w;
    int a = (int)((sqrtf(8.0f * (float)T + 1.0f) - 1.0f) * 0.5f);
    while ((a + 1) * (a + 2) / 2 <= T) ++a;
    while (a * (a + 1) / 2 > T) --a;
    const int b = T - a * (a + 1) / 2;
    const int j0 = a * 16;
    const int i0 = b * 16;
    const bool offdiag = (a != b);

    const float* xj = x + (size_t)(j0 + c) * FD;
    float jA[8], jB[8];
#pragma unroll
    for (int t = 0; t < 4; ++t) {
      jA[t] = xj[q * 8 + t];      jA[4 + t] = xj[q * 8 + 4 + t];
      jB[t] = xj[32 + q * 8 + t]; jB[4 + t] = xj[32 + q * 8 + 4 + t];
    }

    const floatx4 psA_j = *(const floatx4*)(pre + (j0 + c) * HD + q * 4);
    const floatx4 psB_j = *(const floatx4*)(pre + (j0 + c) * HD + 16 + q * 4);
    const floatx4 pdA_j = *(const floatx4*)(pre + NN * HD + (j0 + c) * HD + q * 4);
    const floatx4 pdB_j = *(const floatx4*)(pre + NN * HD + (j0 + c) * HD + 16 + q * 4);
    const floatx4 w2A = *(const floatx4*)(W2 + q * 4);
    const floatx4 w2B = *(const floatx4*)(W2 + 16 + q * 4);
    const float b2v = b2[0];

    for (int ii = 0; ii < 16; ++ii) {
      const int i = i0 + ii;
      const float* xi = x + (size_t)i * FD;
      const floatx4 psA_i = *(const floatx4*)(pre + i * HD + q * 4);
      const floatx4 psB_i = *(const floatx4*)(pre + i * HD + 16 + q * 4);
      floatx4 acc0 = {0.0f, 0.0f, 0.0f, 0.0f};
      floatx4 acc1 = {0.0f, 0.0f, 0.0f, 0.0f};

      {
        const floatx4 i0v = *(const floatx4*)(xi + q * 8);
        const floatx4 i1v = *(const floatx4*)(xi + q * 8 + 4);
        float ad[8], pr[8];
#pragma unroll
        for (int t = 0; t < 4; ++t) {
          ad[t] = fabsf(i0v[t] - jA[t]);         pr[t] = i0v[t] * jA[t];
          ad[4 + t] = fabsf(i1v[t] - jA[4 + t]); pr[4 + t] = i1v[t] * jA[4 + t];
        }
        const short8 fad = pack8(ad);
        const short8 fpr = pack8(pr);
        const short8 A00 = *(const short8*)(sWt0 + c * WSTRIDE + q * 8);
        const short8 A10 = *(const short8*)(sWt0 + (16 + c) * WSTRIDE + q * 8);
        const short8 A02 = *(const short8*)(sWt0 + c * WSTRIDE + 64 + q * 8);
        const short8 A12 = *(const short8*)(sWt0 + (16 + c) * WSTRIDE + 64 + q * 8);
        acc0 = __builtin_amdgcn_mfma_f32_16x16x32_bf16(A00, fad, acc0, 0, 0, 0);
        acc1 = __builtin_amdgcn_mfma_f32_16x16x32_bf16(A10, fad, acc1, 0, 0, 0);
        acc0 = __builtin_amdgcn_mfma_f32_16x16x32_bf16(A02, fpr, acc0, 0, 0, 0);
        acc1 = __builtin_amdgcn_mfma_f32_16x16x32_bf16(A12, fpr, acc1, 0, 0, 0);
      }
      {
        const floatx4 i0v = *(const floatx4*)(xi + 32 + q * 8);
        const floatx4 i1v = *(const floatx4*)(xi + 32 + q * 8 + 4);
        float ad[8], pr[8];
#pragma unroll
        for (int t = 0; t < 4; ++t) {
          ad[t] = fabsf(i0v[t] - jB[t]);         pr[t] = i0v[t] * jB[t];
          ad[4 + t] = fabsf(i1v[t] - jB[4 + t]); pr[4 + t] = i1v[t] * jB[4 + t];
        }
        const short8 fad = pack8(ad);
        const short8 fpr = pack8(pr);
        const short8 A01 = *(const short8*)(sWt0 + c * WSTRIDE + 32 + q * 8);
        const short8 A11 = *(const short8*)(sWt0 + (16 + c) * WSTRIDE + 32 + q * 8);
        const short8 A03 = *(const short8*)(sWt0 + c * WSTRIDE + 96 + q * 8);
        const short8 A13 = *(const short8*)(sWt0 + (16 + c) * WSTRIDE + 96 + q * 8);
        acc0 = __builtin_amdgcn_mfma_f32_16x16x32_bf16(A01, fad, acc0, 0, 0, 0);
        acc1 = __builtin_amdgcn_mfma_f32_16x16x32_bf16(A11, fad, acc1, 0, 0, 0);
        acc0 = __builtin_amdgcn_mfma_f32_16x16x32_bf16(A03, fpr, acc0, 0, 0, 0);
        acc1 = __builtin_amdgcn_mfma_f32_16x16x32_bf16(A13, fpr, acc1, 0, 0, 0);
      }

      // forward: P[i][j0+c]
      float tv = 0.0f;
#pragma unroll
      for (int r = 0; r < 4; ++r) {
        tv = fmaf(fmaxf(acc0[r] + psA_i[r] + pdA_j[r], 0.0f), w2A[r], tv);
        tv = fmaf(fmaxf(acc1[r] + psB_i[r] + pdB_j[r], 0.0f), w2B[r], tv);
      }
      tv += __shfl_xor(tv, 16);
      tv += __shfl_xor(tv, 32);
      if (lane < 16) {
        outP[(size_t)i * NN + j0 + lane] = sigmoid_fast(tv + b2v);
      }

      if (offdiag) {
        const floatx4 pdA_i = *(const floatx4*)(pre + NN * HD + i * HD + q * 4);
        const floatx4 pdB_i = *(const floatx4*)(pre + NN * HD + i * HD + 16 + q * 4);
        float tm = 0.0f;
#pragma unroll
        for (int r = 0; r < 4; ++r) {
          tm = fmaf(fmaxf(acc0[r] + psA_j[r] + pdA_i[r], 0.0f), w2A[r], tm);
          tm = fmaf(fmaxf(acc1[r] + psB_j[r] + pdB_i[r], 0.0f), w2B[r], tm);
        }
        tm += __shfl_xor(tm, 16);
        tm += __shfl_xor(tm, 32);
        if (lane < 16) {
          mir[w][ii * 16 + lane] = sigmoid_fast(tm + b2v);
        }
      }
    }

    if (offdiag) {
      // coalesced mirror store: 16 rows x 64B contiguous segments
      const int r = lane >> 2;
      const int g = lane & 3;
      floatx4 v;
#pragma unroll
      for (int t = 0; t < 4; ++t) v[t] = mir[w][(4 * g + t) * 16 + r];
      *(floatx4*)(outP + (size_t)(j0 + r) * NN + i0 + 4 * g) = v;
    }
  } else {
    // ---------------- edge path: split-MFMA, fp32-accurate ----------------
    const int e0 = ((blockIdx.x - DENSE_BLOCKS) * 4 + w) * 16;

    const bool is64 = (eidx[1] == 0) && (eidx[3] == 0) && (eidx[5] == 0);
    int s_c, d_c;
    if (is64) {
      s_c = eidx[2 * (e0 + c)];
      d_c = eidx[2 * (EE + e0 + c)];
    } else {
      s_c = eidx[e0 + c];
      d_c = eidx[EE + e0 + c];
    }
    const float* xs = x + (size_t)s_c * FD;
    const float* xd = x + (size_t)d_c * FD;

    floatx4 acc0, acc1;
    {
      const floatx4 psA = *(const floatx4*)(pre + s_c * HD + q * 4);
      const floatx4 psB = *(const floatx4*)(pre + s_c * HD + 16 + q * 4);
      const floatx4 pdA = *(const floatx4*)(pre + NN * HD + d_c * HD + q * 4);
      const floatx4 pdB = *(const floatx4*)(pre + NN * HD + d_c * HD + 16 + q * 4);
#pragma unroll
      for (int r = 0; r < 4; ++r) {
        acc0[r] = psA[r] + pdA[r];
        acc1[r] = psB[r] + pdB[r];
      }
    }

    {
      const floatx4 s0 = *(const floatx4*)(xs + q * 8);
      const floatx4 s1 = *(const floatx4*)(xs + q * 8 + 4);
      const floatx4 d0 = *(const floatx4*)(xd + q * 8);
      const floatx4 d1 = *(const floatx4*)(xd + q * 8 + 4);
      float ad[8], pr[8];
#pragma unroll
      for (int t = 0; t < 4; ++t) {
        ad[t] = fabsf(s0[t] - d0[t]);     pr[t] = s0[t] * d0[t];
        ad[4 + t] = fabsf(s1[t] - d1[t]); pr[4 + t] = s1[t] * d1[t];
      }
      edge_chunk(ad, sWt0, sWt1, sWt2, c, q, 0, acc0, acc1);
      edge_chunk(pr, sWt0, sWt1, sWt2, c, q, 2, acc0, acc1);
    }
    {
      const floatx4 s0 = *(const floatx4*)(xs + 32 + q * 8);
      const floatx4 s1 = *(const floatx4*)(xs + 32 + q * 8 + 4);
      const floatx4 d0 = *(const floatx4*)(xd + 32 + q * 8);
      const floatx4 d1 = *(const floatx4*)(xd + 32 + q * 8 + 4);
      float ad[8], pr[8];
#pragma unroll
      for (int t = 0; t < 4; ++t) {
        ad[t] = fabsf(s0[t] - d0[t]);     pr[t] = s0[t] * d0[t];
        ad[4 + t] = fabsf(s1[t] - d1[t]); pr[4 + t] = s1[t] * d1[t];
      }
      edge_chunk(ad, sWt0, sWt1, sWt2, c, q, 1, acc0, acc1);
      edge_chunk(pr, sWt0, sWt1, sWt2, c, q, 3, acc0, acc1);
    }

    const floatx4 w2A = *(const floatx4*)(W2 + q * 4);
    const floatx4 w2B = *(const floatx4*)(W2 + 16 + q * 4);
    float tv = 0.0f;
#pragma unroll
    for (int r = 0; r < 4; ++r) {
      tv = fmaf(fmaxf(acc0[r], 0.0f), w2A[r], tv);
      tv = fmaf(fmaxf(acc1[r], 0.0f), w2B[r], tv);
    }
    tv += __shfl_xor(tv, 16);
    tv += __shfl_xor(tv, 32);
    if (lane < 16) {
      const int e = e0 + lane;
      const float z = tv + b2[0];
      out[e] = sigmoid_f(z);
      out[EE + e] = (z > -0.40546510810816444f) ? 1.0f : 0.0f;
    }
  }
}

// ---------------------------------------------------------------------------
// Fallbacks (no-workspace path)
// ---------------------------------------------------------------------------
__device__ __forceinline__ float pair_logit_full(
    const float* __restrict__ xs, const float* __restrict__ xd,
    const float* __restrict__ W1, const float* __restrict__ b1,
    const float* __restrict__ W2, const float b2v) {
  float acc[HD];
#pragma unroll
  for (int h = 0; h < HD; ++h) acc[h] = b1[h];
#pragma unroll 1
  for (int f = 0; f < FD; ++f) {
    const float a = xs[f], b = xd[f];
    const float ad = fabsf(a - b), pr = a * b;
#pragma unroll
    for (int h = 0; h < HD; ++h) {
      float t0 = fmaf(a, W1[f * HD + h], acc[h]);
      t0 = fmaf(b, W1[(FD + f) * HD + h], t0);
      t0 = fmaf(ad, W1[(2 * FD + f) * HD + h], t0);
      acc[h] = fmaf(pr, W1[(3 * FD + f) * HD + h], t0);
    }
  }
  float z = b2v;
#pragma unroll
  for (int h = 0; h < HD; ++h) z = fmaf(fmaxf(acc[h], 0.0f), W2[h], z);
  return z;
}

__global__ __launch_bounds__(256) void edge_kernel_fb(
    const float* __restrict__ x, const int* __restrict__ eidx,
    const float* __restrict__ W1, const float* __restrict__ b1,
    const float* __restrict__ W2, const float* __restrict__ b2,
    float* __restrict__ out) {
  const int e = blockIdx.x * 256 + threadIdx.x;
  const bool is64 = (eidx[1] == 0) && (eidx[3] == 0) && (eidx[5] == 0);
  int s, d;
  if (is64) { s = eidx[2 * e]; d = eidx[2 * (EE + e)]; }
  else { s = eidx[e]; d = eidx[EE + e]; }
  const float z = pair_logit_full(x + (size_t)s * FD, x + (size_t)d * FD,
                                  W1, b1, W2, b2[0]);
  const float p = sigmoid_f(z);
  out[e] = p;
  out[EE + e] = (p > 0.4f) ? 1.0f : 0.0f;
}

__global__ __launch_bounds__(256) void dense_full_fb(
    const float* __restrict__ x, const float* __restrict__ W1,
    const float* __restrict__ b1, const float* __restrict__ W2,
    const float* __restrict__ b2, float* __restrict__ outP) {
  const int j = blockIdx.x * 64 + threadIdx.x % 64;
  const int i = blockIdx.y * 4 + threadIdx.x / 64;
  const float z = pair_logit_full(x + (size_t)i * FD, x + (size_t)j * FD,
                                  W1, b1, W2, b2[0]);
  outP[(size_t)i * NN + j] = sigmoid_f(z);
}

extern "C" void kernel_launch(void* const* d_in, const int* in_sizes, int n_in,
                              void* d_out, int out_size, void* d_ws, size_t ws_size,
                              hipStream_t stream) {
  const float* x  = (const float*)d_in[0];
  const int*  ei  = (const int*)d_in[1];
  const float* W1 = (const float*)d_in[3];
  const float* b1 = (const float*)d_in[4];
  const float* W2 = (const float*)d_in[5];
  const float* b2 = (const float*)d_in[6];
  float* out  = (float*)d_out;   // [0,EE) probs, [EE,2EE) actions
  float* outP = out + 2 * EE;    // [2EE, 2EE+NN*NN) P

  const size_t pre_bytes = (size_t)2 * NN * HD * sizeof(float);
  const size_t wt_elems = 32 * 128;
  const size_t need = pre_bytes + 3 * wt_elems * sizeof(short);
  if (ws_size >= need) {
    float* pre = (float*)d_ws;
    short* Wt0 = (short*)((char*)d_ws + pre_bytes);
    short* Wt1 = Wt0 + wt_elems;
    short* Wt2 = Wt1 + wt_elems;
    pre_kernel3<<<257, 256, 0, stream>>>(x, W1, b1, pre, Wt0, Wt1, Wt2);
    fused_mfma_kernel<<<DENSE_BLOCKS + 1024, 256, 0, stream>>>(
        x, ei, pre, Wt0, Wt1, Wt2, W2, b2, out, outP);
  } else {
    edge_kernel_fb<<<EE / 256, 256, 0, stream>>>(x, ei, W1, b1, W2, b2, out);
    dense_full_fb<<<dim3(NN / 64, NN / 4), 256, 0, stream>>>(
        x, W1, b1, W2, b2, outP);
  }
}